// Round 3
// baseline (523.527 us; speedup 1.0000x reference)
//
#include <hip/hip_runtime.h>
#include <hip/hip_bf16.h>

// GAT layer, N=8192, DIN=256, DOUT=128.
// h = x@W+bW; e_ij = leaky_relu(s_src[i]+s_dst[j]+ba); p = adj ? exp(e) : 0
// (no max-subtraction: |e| <= ~10 unmasked, fp32-safe). out_i = (sum_j p_ij h_j)/(sum_j p_ij).
//
// R3: two-pass attention. R1/R2 both hit a ~230us latency wall: the in-order
// vmcnt forces each MFMA's wait for its (L2-fast) hbT loads to also drain the
// older in-flight HBM adj prefetch -> every iteration eats a loaded-HBM
// round-trip. Fix: (a) build_mask streams adj (268 MB, the compulsory HBM
// traffic) into a 1-bit/edge mask (8 MB) with zero dependent work - memcpy-like,
// saturates HBM; (b) gat_attn's loop then touches ONLY cache-resident data
// (mask 8MB L2/L3, s_dst 32KB, hbT 2MB L2) so vmcnt drains cost ~L2 latency.

#define NN 8192
#define DIN 256
#define DOUT 128

typedef __attribute__((ext_vector_type(8))) short short8;   // 8 bf16 = 4 VGPRs (MFMA A/B frag)
typedef __attribute__((ext_vector_type(4))) float floatx4;  // MFMA C/D frag

// ---------------- kernel 0: W [256][128] fp32 -> WT [128][256] bf16 ----------------
__global__ void prep_wt(const float* __restrict__ W, __hip_bfloat16* __restrict__ WT) {
    int e = blockIdx.x * blockDim.x + threadIdx.x;
    if (e < DIN * DOUT) {
        int k = e >> 7;
        int d = e & 127;
        WT[d * DIN + k] = __float2bfloat16(W[e]);
    }
}

// ---------------- kernel 1: h = x@W + bW (MFMA), fused s_src/s_dst, store hbT ----------------
__global__ __launch_bounds__(256, 4) void gat_h(
    const float* __restrict__ x, const __hip_bfloat16* __restrict__ WT,
    const float* __restrict__ bW, const float* __restrict__ a1, const float* __restrict__ a2,
    __hip_bfloat16* __restrict__ hbT, float* __restrict__ s_src, float* __restrict__ s_dst) {
    int tid = threadIdx.x;
    int w = tid >> 6, lane = tid & 63;
    int lm = lane & 15, lq = lane >> 4;
    int i0 = blockIdx.x * 32;
    int r0 = (w >> 1) * 16;
    int c0 = (w & 1) * 64;

    __shared__ float s1s[32], s2s[32];
    if (tid < 32) { s1s[tid] = 0.f; s2s[tid] = 0.f; }
    __syncthreads();

    floatx4 acc[4] = {};
#pragma unroll
    for (int kk = 0; kk < DIN; kk += 32) {
        const float4* xp = (const float4*)&x[(size_t)(i0 + r0 + lm) * DIN + kk + lq * 8];
        float4 xa = xp[0], xb = xp[1];
        union { short8 v; __hip_bfloat16 h[8]; } af;
        af.h[0] = __float2bfloat16(xa.x); af.h[1] = __float2bfloat16(xa.y);
        af.h[2] = __float2bfloat16(xa.z); af.h[3] = __float2bfloat16(xa.w);
        af.h[4] = __float2bfloat16(xb.x); af.h[5] = __float2bfloat16(xb.y);
        af.h[6] = __float2bfloat16(xb.z); af.h[7] = __float2bfloat16(xb.w);
#pragma unroll
        for (int t = 0; t < 4; t++) {
            int d = c0 + 16 * t + lm;
            short8 bf = *(const short8*)&WT[(size_t)d * DIN + kk + lq * 8];
            acc[t] = __builtin_amdgcn_mfma_f32_16x16x32_bf16(af.v, bf, acc[t], 0, 0, 0);
        }
    }
    float s1[4] = {0.f, 0.f, 0.f, 0.f}, s2[4] = {0.f, 0.f, 0.f, 0.f};
#pragma unroll
    for (int t = 0; t < 4; t++) {
        int d = c0 + 16 * t + lm;
        float A1 = a1[d], A2 = a2[d], B = bW[d];
#pragma unroll
        for (int r = 0; r < 4; r++) {
            int row = r0 + lq * 4 + r;
            float h = acc[t][r] + B;
            hbT[(size_t)d * NN + i0 + row] = __float2bfloat16(h);
            s1[r] += h * A1;
            s2[r] += h * A2;
        }
    }
#pragma unroll
    for (int r = 0; r < 4; r++) {
        for (int m = 1; m < 16; m <<= 1) {
            s1[r] += __shfl_xor(s1[r], m, 64);
            s2[r] += __shfl_xor(s2[r], m, 64);
        }
    }
    if (lm == 0) {
#pragma unroll
        for (int r = 0; r < 4; r++) {
            int row = r0 + lq * 4 + r;
            atomicAdd(&s1s[row], s1[r]);
            atomicAdd(&s2s[row], s2[r]);
        }
    }
    __syncthreads();
    if (tid < 32) {
        s_src[i0 + tid] = s1s[tid];
        s_dst[i0 + tid] = s2s[tid];
    }
}

// ---------------- kernel 2: adj int32 -> 1-bit mask (byte per 8 j) ----------------
// thread t: reads adj[t*8 .. t*8+7] (2x int4, 32B), writes mask byte t.
// Pure stream: 268 MB read / 8.4 MB write, no dependent chains -> HBM-saturating.
__global__ void build_mask(const int* __restrict__ adj, unsigned char* __restrict__ mask) {
    size_t gid = (size_t)blockIdx.x * blockDim.x + threadIdx.x;  // 8,388,608 threads
    const int4* a = (const int4*)(adj + gid * 8);
    int4 v0 = a[0], v1 = a[1];
    unsigned int b = 0;
    b |= (v0.x != 0) ? 1u : 0u;
    b |= (v0.y != 0) ? 2u : 0u;
    b |= (v0.z != 0) ? 4u : 0u;
    b |= (v0.w != 0) ? 8u : 0u;
    b |= (v1.x != 0) ? 16u : 0u;
    b |= (v1.y != 0) ? 32u : 0u;
    b |= (v1.z != 0) ? 64u : 0u;
    b |= (v1.w != 0) ? 128u : 0u;
    mask[gid] = (unsigned char)b;
}

// ---------------- kernel 3: masked softmax-weighted GEMM, cache-resident loop ----------------
// grid = 128 row-blocks x JSPLIT. 4 waves; wave w owns rows ib*64+w*16 and all 128 dims.
// Loop loads: mask byte (L2/L3), s_dst 2xfloat4 (L2), hbT 8xshort8 (L2). No HBM stream.
template <int NJT>
__global__ __launch_bounds__(256, 4) void gat_attn(
    const unsigned char* __restrict__ mask, const float* __restrict__ s_src,
    const float* __restrict__ s_dst, const float* __restrict__ ba_p,
    const __hip_bfloat16* __restrict__ hbT,
    float* __restrict__ num, float* __restrict__ lpart) {
    int tid = threadIdx.x;
    int w = tid >> 6, lane = tid & 63;
    int lm = lane & 15, lq = lane >> 4;
    int b = blockIdx.x;
    int ib = b & 127;
    int jh = b >> 7;
    int i0 = ib * 64 + w * 16;
    int jb0 = jh * (NJT * 32);

    float ssi = s_src[i0 + lm] + ba_p[0];

    const unsigned char* mrow = mask + (size_t)(i0 + lm) * (NN / 8) + (jb0 >> 3) + lq;
    const float* sd = s_dst + jb0 + lq * 8;
    const __hip_bfloat16* hbb = hbT + (size_t)lm * NN + jb0 + lq * 8;

    floatx4 acc[8] = {};
    floatx4 accd = {};
    const short8 ones = { 0x3F80, 0x3F80, 0x3F80, 0x3F80, 0x3F80, 0x3F80, 0x3F80, 0x3F80 };

    // depth-2 pipeline on mask + s_dst (everything is cache-resident; this just
    // keeps the consuming waitcnt off the critical path)
    unsigned int mA = mrow[0];
    float4 dA0 = *(const float4*)sd;
    float4 dA1 = *(const float4*)(sd + 4);
    unsigned int mB = mrow[4];
    float4 dB0 = *(const float4*)(sd + 32);
    float4 dB1 = *(const float4*)(sd + 36);

#pragma unroll 4
    for (int t = 0; t < NJT; t++) {
        unsigned int cm = mA;
        float4 cd0 = dA0, cd1 = dA1;
        mA = mB; dA0 = dB0; dA1 = dB1;
        if (t + 2 < NJT) {
            mB = mrow[(t + 2) * 4];
            dB0 = *(const float4*)(sd + (t + 2) * 32);
            dB1 = *(const float4*)(sd + (t + 2) * 32 + 4);
        }
        float p[8];
        {
            float e;
            e = ssi + cd0.x; e = fmaxf(e, 0.01f * e); p[0] = (cm & 1u)   ? __expf(e) : 0.f;
            e = ssi + cd0.y; e = fmaxf(e, 0.01f * e); p[1] = (cm & 2u)   ? __expf(e) : 0.f;
            e = ssi + cd0.z; e = fmaxf(e, 0.01f * e); p[2] = (cm & 4u)   ? __expf(e) : 0.f;
            e = ssi + cd0.w; e = fmaxf(e, 0.01f * e); p[3] = (cm & 8u)   ? __expf(e) : 0.f;
            e = ssi + cd1.x; e = fmaxf(e, 0.01f * e); p[4] = (cm & 16u)  ? __expf(e) : 0.f;
            e = ssi + cd1.y; e = fmaxf(e, 0.01f * e); p[5] = (cm & 32u)  ? __expf(e) : 0.f;
            e = ssi + cd1.z; e = fmaxf(e, 0.01f * e); p[6] = (cm & 64u)  ? __expf(e) : 0.f;
            e = ssi + cd1.w; e = fmaxf(e, 0.01f * e); p[7] = (cm & 128u) ? __expf(e) : 0.f;
        }
        union { short8 v; __hip_bfloat162 q[4]; } af;
        af.q[0] = __float22bfloat162_rn(make_float2(p[0], p[1]));
        af.q[1] = __float22bfloat162_rn(make_float2(p[2], p[3]));
        af.q[2] = __float22bfloat162_rn(make_float2(p[4], p[5]));
        af.q[3] = __float22bfloat162_rn(make_float2(p[6], p[7]));

        size_t off = (size_t)t * 32;
#pragma unroll
        for (int f = 0; f < 8; f++) {
            short8 bf = *(const short8*)(hbb + (size_t)f * 16 * NN + off);
            acc[f] = __builtin_amdgcn_mfma_f32_16x16x32_bf16(af.v, bf, acc[f], 0, 0, 0);
        }
        accd = __builtin_amdgcn_mfma_f32_16x16x32_bf16(af.v, ones, accd, 0, 0, 0);
    }

    // epilogue: C/D layout col=lm, row=lq*4+r
    float* nb = num + ((size_t)(b >> 7) * NN + i0) * DOUT;
#pragma unroll
    for (int f = 0; f < 8; f++)
#pragma unroll
        for (int r = 0; r < 4; r++)
            nb[(size_t)(lq * 4 + r) * DOUT + f * 16 + lm] = acc[f][r];
    if (lm == 0) {
#pragma unroll
        for (int r = 0; r < 4; r++)
            lpart[(size_t)(b >> 7) * NN + i0 + lq * 4 + r] = accd[r];
    }
}

// ---------------- kernel 4: combine partials, divide ----------------
__global__ void gat_combine(const float* __restrict__ num, const float* __restrict__ lpart,
                            float* __restrict__ out, int jsplit) {
    int gid = blockIdx.x * blockDim.x + threadIdx.x;  // 262144 threads, one float4 each
    int idx = gid * 4;
    int i = idx >> 7;
    float den = 0.f;
    for (int s = 0; s < jsplit; s++) den += lpart[(size_t)s * NN + i];
    float inv = 1.0f / den;
    float4 o = make_float4(0.f, 0.f, 0.f, 0.f);
    for (int s = 0; s < jsplit; s++) {
        float4 n = *(const float4*)&num[(size_t)s * NN * DOUT + idx];
        o.x += n.x; o.y += n.y; o.z += n.z; o.w += n.w;
    }
    o.x *= inv; o.y *= inv; o.z *= inv; o.w *= inv;
    *(float4*)&out[idx] = o;
}

extern "C" void kernel_launch(void* const* d_in, const int* in_sizes, int n_in,
                              void* d_out, int out_size, void* d_ws, size_t ws_size,
                              hipStream_t stream) {
    const float* x  = (const float*)d_in[0];
    const int* adj  = (const int*)d_in[1];
    const float* W  = (const float*)d_in[2];
    const float* bW = (const float*)d_in[3];
    const float* a1 = (const float*)d_in[4];
    const float* a2 = (const float*)d_in[5];
    const float* ba = (const float*)d_in[6];
    float* out = (float*)d_out;

    char* ws = (char*)d_ws;
    __hip_bfloat16* hbT  = (__hip_bfloat16*)ws;                    // 2 MB   [128][8192]
    __hip_bfloat16* WT   = (__hip_bfloat16*)(ws + 2097152);        // 64 KB
    float* s_src         = (float*)(ws + 2162688);                 // 32 KB
    float* s_dst         = (float*)(ws + 2195456);                 // 32 KB
    float* lpart         = (float*)(ws + 2228224);                 // 256 KB [<=8][8192]
    unsigned char* mask  = (unsigned char*)(ws + 2490368);         // 8 MB   [8192][1024]
    float* num           = (float*)(ws + 10878976);                // jsplit*4 MB

    int jsplit = (ws_size >= 10878976 + (size_t)8 * NN * DOUT * 4) ? 8 : 4;

    prep_wt<<<128, 256, 0, stream>>>(W, WT);
    gat_h<<<256, 256, 0, stream>>>(x, WT, bW, a1, a2, hbT, s_src, s_dst);
    build_mask<<<32768, 256, 0, stream>>>(adj, mask);
    if (jsplit == 8)
        gat_attn<32><<<1024, 256, 0, stream>>>(mask, s_src, s_dst, ba, hbT, num, lpart);
    else
        gat_attn<64><<<512, 256, 0, stream>>>(mask, s_src, s_dst, ba, hbT, num, lpart);
    gat_combine<<<1024, 256, 0, stream>>>(num, lpart, out, jsplit);
}

// Round 4
// 504.115 us; speedup vs baseline: 1.0385x; 1.0385x over previous
//
#include <hip/hip_runtime.h>
#include <hip/hip_bf16.h>

// GAT layer, N=8192, DIN=256, DOUT=128.
// h = x@W+bW; e_ij = leaky_relu(s_src[i]+s_dst[j]+ba); p = adj ? exp(e) : 0
// (no max-subtraction: |e| <= ~10 unmasked, fp32-safe). out_i = (sum_j p_ij h_j)/(sum_j p_ij).
//
// R4: single fused attention kernel, two phases per wave, no LDS, no barriers.
//  Phase A: stream this wave's adj slice (16 rows x NJT*32 j) -> 1 bit/edge
//           packed into NJT/4 VGPRs. Pure streaming (no dependent math), so the
//           compulsory 268 MB adj read runs memcpy-like at HBM rate.
//  Phase B: R3's register-A-fragment MFMA loop, but mask comes from VGPRs,
//           s_dst/hbT from L1/L2 -> no HBM in the loop, no in-order-vmcnt
//           drain of slow loads (the R1/R2 230us wall).
// log2(e) is folded into s_src/s_dst (gat_h epilogue) so phase B uses raw
// v_exp_f32 (2^x): LR commutes with positive scaling.

#define NN 8192
#define DIN 256
#define DOUT 128
#define LOG2E 1.4426950408889634f

typedef __attribute__((ext_vector_type(8))) short short8;   // 8 bf16 = 4 VGPRs (MFMA A/B frag)
typedef __attribute__((ext_vector_type(4))) float floatx4;  // MFMA C/D frag

// ---------------- kernel 0: W [256][128] fp32 -> WT [128][256] bf16 ----------------
__global__ void prep_wt(const float* __restrict__ W, __hip_bfloat16* __restrict__ WT) {
    int e = blockIdx.x * blockDim.x + threadIdx.x;
    if (e < DIN * DOUT) {
        int k = e >> 7;
        int d = e & 127;
        WT[d * DIN + k] = __float2bfloat16(W[e]);
    }
}

// ---------------- kernel 1: h = x@W + bW (MFMA), fused s_src/s_dst (pre-scaled by log2e) ----------------
__global__ __launch_bounds__(256, 4) void gat_h(
    const float* __restrict__ x, const __hip_bfloat16* __restrict__ WT,
    const float* __restrict__ bW, const float* __restrict__ a1, const float* __restrict__ a2,
    __hip_bfloat16* __restrict__ hbT, float* __restrict__ s_src, float* __restrict__ s_dst) {
    int tid = threadIdx.x;
    int w = tid >> 6, lane = tid & 63;
    int lm = lane & 15, lq = lane >> 4;
    int i0 = blockIdx.x * 32;
    int r0 = (w >> 1) * 16;
    int c0 = (w & 1) * 64;

    __shared__ float s1s[32], s2s[32];
    if (tid < 32) { s1s[tid] = 0.f; s2s[tid] = 0.f; }
    __syncthreads();

    floatx4 acc[4] = {};
#pragma unroll
    for (int kk = 0; kk < DIN; kk += 32) {
        const float4* xp = (const float4*)&x[(size_t)(i0 + r0 + lm) * DIN + kk + lq * 8];
        float4 xa = xp[0], xb = xp[1];
        union { short8 v; __hip_bfloat16 h[8]; } af;
        af.h[0] = __float2bfloat16(xa.x); af.h[1] = __float2bfloat16(xa.y);
        af.h[2] = __float2bfloat16(xa.z); af.h[3] = __float2bfloat16(xa.w);
        af.h[4] = __float2bfloat16(xb.x); af.h[5] = __float2bfloat16(xb.y);
        af.h[6] = __float2bfloat16(xb.z); af.h[7] = __float2bfloat16(xb.w);
#pragma unroll
        for (int t = 0; t < 4; t++) {
            int d = c0 + 16 * t + lm;
            short8 bf = *(const short8*)&WT[(size_t)d * DIN + kk + lq * 8];
            acc[t] = __builtin_amdgcn_mfma_f32_16x16x32_bf16(af.v, bf, acc[t], 0, 0, 0);
        }
    }
    float s1[4] = {0.f, 0.f, 0.f, 0.f}, s2[4] = {0.f, 0.f, 0.f, 0.f};
#pragma unroll
    for (int t = 0; t < 4; t++) {
        int d = c0 + 16 * t + lm;
        float A1 = a1[d], A2 = a2[d], B = bW[d];
#pragma unroll
        for (int r = 0; r < 4; r++) {
            int row = r0 + lq * 4 + r;
            float h = acc[t][r] + B;
            hbT[(size_t)d * NN + i0 + row] = __float2bfloat16(h);
            s1[r] += h * A1;
            s2[r] += h * A2;
        }
    }
#pragma unroll
    for (int r = 0; r < 4; r++) {
        for (int m = 1; m < 16; m <<= 1) {
            s1[r] += __shfl_xor(s1[r], m, 64);
            s2[r] += __shfl_xor(s2[r], m, 64);
        }
    }
    if (lm == 0) {
#pragma unroll
        for (int r = 0; r < 4; r++) {
            int row = r0 + lq * 4 + r;
            atomicAdd(&s1s[row], s1[r]);
            atomicAdd(&s2s[row], s2[r]);
        }
    }
    __syncthreads();
    if (tid < 32) {
        s_src[i0 + tid] = s1s[tid] * LOG2E;   // pre-scale: exp(e) = exp2(e*log2e)
        s_dst[i0 + tid] = s2s[tid] * LOG2E;
    }
}

// ---------------- kernel 2: fused mask-build + masked softmax-weighted GEMM ----------------
// grid = 128 row-blocks x JSPLIT. 4 waves; wave w owns rows ib*64+w*16 and all 128 dims.
template <int NJT>
__global__ __launch_bounds__(256, 4) void gat_attn(
    const int* __restrict__ adj, const float* __restrict__ s_src,
    const float* __restrict__ s_dst, const float* __restrict__ ba_p,
    const __hip_bfloat16* __restrict__ hbT,
    float* __restrict__ num, float* __restrict__ lpart) {
    int tid = threadIdx.x;
    int w = tid >> 6, lane = tid & 63;
    int lm = lane & 15, lq = lane >> 4;
    int b = blockIdx.x;
    int ib = b & 127;
    int jh = b >> 7;
    int i0 = ib * 64 + w * 16;
    int jb0 = jh * (NJT * 32);

    // ---- phase A: stream adj slice -> packed mask bits in VGPRs ----
    // lane (lm,lq) needs j = t*32 + lq*8 .. +7 for t=0..NJT-1 (its A-frag slots).
    const int* arow = adj + (size_t)(i0 + lm) * NN + jb0 + lq * 8;
    unsigned int mreg[NJT / 4];
#pragma unroll
    for (int t = 0; t < NJT; t++) {
        const int4* ap = (const int4*)(arow + t * 32);
        int4 v0 = ap[0], v1 = ap[1];
        unsigned int bb = 0;
        bb |= (v0.x != 0) ? 1u : 0u;
        bb |= (v0.y != 0) ? 2u : 0u;
        bb |= (v0.z != 0) ? 4u : 0u;
        bb |= (v0.w != 0) ? 8u : 0u;
        bb |= (v1.x != 0) ? 16u : 0u;
        bb |= (v1.y != 0) ? 32u : 0u;
        bb |= (v1.z != 0) ? 64u : 0u;
        bb |= (v1.w != 0) ? 128u : 0u;
        if ((t & 3) == 0) mreg[t >> 2] = bb;
        else              mreg[t >> 2] |= bb << ((t & 3) * 8);
    }

    // ---- phase B: MFMA loop, all loads L1/L2-resident ----
    float ssi = s_src[i0 + lm] + ba_p[0] * LOG2E;
    const float* sd = s_dst + jb0 + lq * 8;
    const __hip_bfloat16* hbb = hbT + (size_t)lm * NN + jb0 + lq * 8;

    floatx4 acc[8] = {};
    floatx4 accd = {};
    const short8 ones = { 0x3F80, 0x3F80, 0x3F80, 0x3F80, 0x3F80, 0x3F80, 0x3F80, 0x3F80 };

#pragma unroll
    for (int t = 0; t < NJT; t++) {
        unsigned int cm = (mreg[t >> 2] >> ((t & 3) * 8)) & 0xFFu;
        float4 cd0 = *(const float4*)(sd + t * 32);
        float4 cd1 = *(const float4*)(sd + t * 32 + 4);
        float p[8];
        {
            float e;
            e = ssi + cd0.x; e = fmaxf(e, 0.01f * e); p[0] = (cm & 1u)   ? __builtin_amdgcn_exp2f(e) : 0.f;
            e = ssi + cd0.y; e = fmaxf(e, 0.01f * e); p[1] = (cm & 2u)   ? __builtin_amdgcn_exp2f(e) : 0.f;
            e = ssi + cd0.z; e = fmaxf(e, 0.01f * e); p[2] = (cm & 4u)   ? __builtin_amdgcn_exp2f(e) : 0.f;
            e = ssi + cd0.w; e = fmaxf(e, 0.01f * e); p[3] = (cm & 8u)   ? __builtin_amdgcn_exp2f(e) : 0.f;
            e = ssi + cd1.x; e = fmaxf(e, 0.01f * e); p[4] = (cm & 16u)  ? __builtin_amdgcn_exp2f(e) : 0.f;
            e = ssi + cd1.y; e = fmaxf(e, 0.01f * e); p[5] = (cm & 32u)  ? __builtin_amdgcn_exp2f(e) : 0.f;
            e = ssi + cd1.z; e = fmaxf(e, 0.01f * e); p[6] = (cm & 64u)  ? __builtin_amdgcn_exp2f(e) : 0.f;
            e = ssi + cd1.w; e = fmaxf(e, 0.01f * e); p[7] = (cm & 128u) ? __builtin_amdgcn_exp2f(e) : 0.f;
        }
        union { short8 v; __hip_bfloat162 q[4]; } af;
        af.q[0] = __float22bfloat162_rn(make_float2(p[0], p[1]));
        af.q[1] = __float22bfloat162_rn(make_float2(p[2], p[3]));
        af.q[2] = __float22bfloat162_rn(make_float2(p[4], p[5]));
        af.q[3] = __float22bfloat162_rn(make_float2(p[6], p[7]));

        size_t off = (size_t)t * 32;
#pragma unroll
        for (int f = 0; f < 8; f++) {
            short8 bf = *(const short8*)(hbb + (size_t)f * 16 * NN + off);
            acc[f] = __builtin_amdgcn_mfma_f32_16x16x32_bf16(af.v, bf, acc[f], 0, 0, 0);
        }
        accd = __builtin_amdgcn_mfma_f32_16x16x32_bf16(af.v, ones, accd, 0, 0, 0);
    }

    // epilogue: C/D layout col=lm, row=lq*4+r
    float* nb = num + ((size_t)jh * NN + i0) * DOUT;
#pragma unroll
    for (int f = 0; f < 8; f++)
#pragma unroll
        for (int r = 0; r < 4; r++)
            nb[(size_t)(lq * 4 + r) * DOUT + f * 16 + lm] = acc[f][r];
    if (lm == 0) {
#pragma unroll
        for (int r = 0; r < 4; r++)
            lpart[(size_t)jh * NN + i0 + lq * 4 + r] = accd[r];
    }
}

// ---------------- kernel 3: combine partials, divide ----------------
__global__ void gat_combine(const float* __restrict__ num, const float* __restrict__ lpart,
                            float* __restrict__ out, int jsplit) {
    int gid = blockIdx.x * blockDim.x + threadIdx.x;  // 262144 threads, one float4 each
    int idx = gid * 4;
    int i = idx >> 7;
    float den = 0.f;
    for (int s = 0; s < jsplit; s++) den += lpart[(size_t)s * NN + i];
    float inv = 1.0f / den;
    float4 o = make_float4(0.f, 0.f, 0.f, 0.f);
    for (int s = 0; s < jsplit; s++) {
        float4 n = *(const float4*)&num[(size_t)s * NN * DOUT + idx];
        o.x += n.x; o.y += n.y; o.z += n.z; o.w += n.w;
    }
    o.x *= inv; o.y *= inv; o.z *= inv; o.w *= inv;
    *(float4*)&out[idx] = o;
}

extern "C" void kernel_launch(void* const* d_in, const int* in_sizes, int n_in,
                              void* d_out, int out_size, void* d_ws, size_t ws_size,
                              hipStream_t stream) {
    const float* x  = (const float*)d_in[0];
    const int* adj  = (const int*)d_in[1];
    const float* W  = (const float*)d_in[2];
    const float* bW = (const float*)d_in[3];
    const float* a1 = (const float*)d_in[4];
    const float* a2 = (const float*)d_in[5];
    const float* ba = (const float*)d_in[6];
    float* out = (float*)d_out;

    char* ws = (char*)d_ws;
    __hip_bfloat16* hbT  = (__hip_bfloat16*)ws;                    // 2 MB   [128][8192]
    __hip_bfloat16* WT   = (__hip_bfloat16*)(ws + 2097152);        // 64 KB
    float* s_src         = (float*)(ws + 2162688);                 // 32 KB (pre-scaled by log2e)
    float* s_dst         = (float*)(ws + 2195456);                 // 32 KB (pre-scaled by log2e)
    float* lpart         = (float*)(ws + 2228224);                 // 256 KB [<=8][8192]
    float* num           = (float*)(ws + 2490368);                 // jsplit*4 MB

    int jsplit = (ws_size >= 2490368 + (size_t)8 * NN * DOUT * 4) ? 8 : 4;

    prep_wt<<<128, 256, 0, stream>>>(W, WT);
    gat_h<<<256, 256, 0, stream>>>(x, WT, bW, a1, a2, hbT, s_src, s_dst);
    if (jsplit == 8)
        gat_attn<32><<<1024, 256, 0, stream>>>(adj, s_src, s_dst, ba, hbT, num, lpart);
    else
        gat_attn<64><<<512, 256, 0, stream>>>(adj, s_src, s_dst, ba, hbT, num, lpart);
    gat_combine<<<1024, 256, 0, stream>>>(num, lpart, out, jsplit);
}